// Round 1
// baseline (343.661 us; speedup 1.0000x reference)
//
#include <hip/hip_runtime.h>
#include <stdint.h>

typedef unsigned short u16;
typedef __bf16 bf16x8 __attribute__((ext_vector_type(8)));
typedef float fx4 __attribute__((ext_vector_type(4)));

// ---------------- helpers ----------------

__device__ __forceinline__ u16 f2bf(float f) {
    unsigned int u = __float_as_uint(f);
    u += 0x7fffu + ((u >> 16) & 1u);   // RNE
    return (u16)(u >> 16);
}

template<int CTRL>
__device__ __forceinline__ float dppmov(float x) {
    return __int_as_float(__builtin_amdgcn_update_dpp(
        __float_as_int(x), __float_as_int(x), CTRL, 0xf, 0xf, false));
}
// reduce across the 16 lanes of a DPP row (our quad-groups are exactly DPP rows)
__device__ __forceinline__ float rowmax16(float x) {
    x = fmaxf(x, dppmov<0x128>(x));  // row_ror:8
    x = fmaxf(x, dppmov<0x124>(x));  // row_ror:4
    x = fmaxf(x, dppmov<0x122>(x));  // row_ror:2
    x = fmaxf(x, dppmov<0x121>(x));  // row_ror:1
    return x;
}
__device__ __forceinline__ float rowsum16(float x) {
    x += dppmov<0x128>(x);
    x += dppmov<0x124>(x);
    x += dppmov<0x122>(x);
    x += dppmov<0x121>(x);
    return x;
}

__device__ __forceinline__ bf16x8 ld8(const u16* p) {
    return __builtin_bit_cast(bf16x8, *(const int4*)p);
}

// ---------------- kernel 0a: cast x -> bf16 ----------------

__global__ __launch_bounds__(256) void cast_x_kernel(const float* __restrict__ x,
                                                     u16* __restrict__ xb) {
    int idx = blockIdx.x * 256 + threadIdx.x;   // 8 elems per thread
    const float4* p = (const float4*)(x + (size_t)idx * 8);
    float4 a = p[0], b = p[1];
    unsigned int u0 = f2bf(a.x) | ((unsigned int)f2bf(a.y) << 16);
    unsigned int u1 = f2bf(a.z) | ((unsigned int)f2bf(a.w) << 16);
    unsigned int u2 = f2bf(b.x) | ((unsigned int)f2bf(b.y) << 16);
    unsigned int u3 = f2bf(b.z) | ((unsigned int)f2bf(b.w) << 16);
    int4 v; v.x = (int)u0; v.y = (int)u1; v.z = (int)u2; v.w = (int)u3;
    *(int4*)(xb + (size_t)idx * 8) = v;
}

// ---------------- kernel 0b: transpose + cast weights ----------------
// in: [NR][NC] fp32 -> out: [NC][NR] bf16

__global__ __launch_bounds__(256) void transpose_cast_kernel(const float* __restrict__ in,
                                                             u16* __restrict__ out,
                                                             int NR, int NC) {
    __shared__ float T[64][65];
    int t = threadIdx.x;
    int i0 = blockIdx.y * 64, j0 = blockIdx.x * 64;
    int r = t >> 4, cc = t & 15;
#pragma unroll
    for (int j = 0; j < 4; ++j) {
        int row = r + j * 16;
        float4 v = *(const float4*)(in + (size_t)(i0 + row) * NC + j0 + cc * 4);
        T[row][cc * 4 + 0] = v.x; T[row][cc * 4 + 1] = v.y;
        T[row][cc * 4 + 2] = v.z; T[row][cc * 4 + 3] = v.w;
    }
    __syncthreads();
#pragma unroll
    for (int j = 0; j < 4; ++j) {
        int jr = r + j * 16;
        unsigned int u0 = f2bf(T[cc * 4 + 0][jr]) | ((unsigned int)f2bf(T[cc * 4 + 1][jr]) << 16);
        unsigned int u1 = f2bf(T[cc * 4 + 2][jr]) | ((unsigned int)f2bf(T[cc * 4 + 3][jr]) << 16);
        uint2 u; u.x = u0; u.y = u1;
        *(uint2*)(out + (size_t)(j0 + jr) * NR + i0 + cc * 4) = u;
    }
}

// ---------------- GEMM: C[M,Ncols] = A[M,512] * Bt[Ncols,512]^T ----------------
// MODE 0: qkv projection -> scatter to Qb (x0.125), Kb [BH][4096][64], Vt [BH][64][4096]
// MODE 1: out projection -> d_out fp32 [8192][512] + bias

template<int MODE>
__global__ __launch_bounds__(256) void gemm_kernel(const u16* __restrict__ A,
                                                   const u16* __restrict__ Bt,
                                                   u16* __restrict__ Qb,
                                                   u16* __restrict__ Kb,
                                                   u16* __restrict__ Vt,
                                                   const float* __restrict__ bias,
                                                   float* __restrict__ Out,
                                                   int Ncols) {
    __shared__ __align__(16) u16 As[128 * 32];
    __shared__ __align__(16) u16 Bs[128 * 32];
    int tid = threadIdx.x;
    int w = tid >> 6, lane = tid & 63;
    int m16 = lane & 15, quad = lane >> 4;
    int ntn = Ncols / 128;
    int bx = blockIdx.x % ntn, by = blockIdx.x / ntn;
    int r0 = by * 128, c0 = bx * 128;
    int wr = w >> 1, wc = w & 1;

    fx4 acc[4][4] = {};

    for (int k0 = 0; k0 < 512; k0 += 32) {
        __syncthreads();
#pragma unroll
        for (int j = 0; j < 2; ++j) {
            int L = tid + j * 256;
            int row = L >> 2, c = L & 3;
            *(int4*)&As[row * 32 + c * 8] = *(const int4*)(A + (size_t)(r0 + row) * 512 + k0 + c * 8);
            *(int4*)&Bs[row * 32 + c * 8] = *(const int4*)(Bt + (size_t)(c0 + row) * 512 + k0 + c * 8);
        }
        __syncthreads();
        bf16x8 af[4], bfr[4];
#pragma unroll
        for (int t = 0; t < 4; ++t) {
            af[t]  = ld8(&As[(wr * 64 + t * 16 + m16) * 32 + quad * 8]);
            bfr[t] = ld8(&Bs[(wc * 64 + t * 16 + m16) * 32 + quad * 8]);
        }
#pragma unroll
        for (int mt = 0; mt < 4; ++mt)
#pragma unroll
            for (int nt = 0; nt < 4; ++nt)
                acc[mt][nt] = __builtin_amdgcn_mfma_f32_16x16x32_bf16(af[mt], bfr[nt], acc[mt][nt], 0, 0, 0);
    }

#pragma unroll
    for (int mt = 0; mt < 4; ++mt) {
        int R0 = r0 + wr * 64 + mt * 16 + quad * 4;   // 4 consecutive rows R0..R0+3
#pragma unroll
        for (int nt = 0; nt < 4; ++nt) {
            int C = c0 + wc * 64 + nt * 16 + m16;
            if (MODE == 0) {
                int sec = C >> 9;                 // 0=q 1=k 2=v (uniform per block)
                int h = (C >> 6) & 7, d = C & 63;
                int b = R0 >> 12, n0 = R0 & 4095;
                size_t hb = (size_t)(b * 8 + h);
                if (sec == 0) {
#pragma unroll
                    for (int r = 0; r < 4; ++r)
                        Qb[(hb * 4096 + n0 + r) * 64 + d] = f2bf(acc[mt][nt][r] * 0.125f);
                } else if (sec == 1) {
#pragma unroll
                    for (int r = 0; r < 4; ++r)
                        Kb[(hb * 4096 + n0 + r) * 64 + d] = f2bf(acc[mt][nt][r]);
                } else {
                    unsigned int u0 = f2bf(acc[mt][nt][0]) | ((unsigned int)f2bf(acc[mt][nt][1]) << 16);
                    unsigned int u1 = f2bf(acc[mt][nt][2]) | ((unsigned int)f2bf(acc[mt][nt][3]) << 16);
                    uint2 u; u.x = u0; u.y = u1;
                    *(uint2*)(Vt + (hb * 64 + d) * 4096 + n0) = u;
                }
            } else {
                float bv = bias[C];
#pragma unroll
                for (int r = 0; r < 4; ++r)
                    Out[(size_t)(R0 + r) * 512 + C] = acc[mt][nt][r] + bv;
            }
        }
    }
}

// ---------------- flash attention ----------------
// grid: 512 = 16 (b,h) * 32 q-tiles of 128 rows. 4 waves, each owns 32 q-rows.

__global__ __launch_bounds__(256) void attn_kernel(const u16* __restrict__ Qb,
                                                   const u16* __restrict__ Kb,
                                                   const u16* __restrict__ Vt,
                                                   u16* __restrict__ Ob) {
    __shared__ __align__(16) u16 Ks[64 * 72];    // rows: key, padded 72
    __shared__ __align__(16) u16 Vs[64 * 72];    // rows: d,   cols: key, padded 72
    __shared__ __align__(16) u16 Ps[128 * 72];   // P tile, padded 72

    int tid = threadIdx.x;
    int w = tid >> 6, lane = tid & 63;
    int m16 = lane & 15, quad = lane >> 4;
    int qt = blockIdx.x & 31, bh = blockIdx.x >> 5;
    int q0 = qt * 128;

    const u16* Qg = Qb + (size_t)bh * 4096 * 64;
    const u16* Kg = Kb + (size_t)bh * 4096 * 64;
    const u16* Vg = Vt + (size_t)bh * 64 * 4096;

    // preload Q fragments (A-operand layout: row = lane&15, k = quad*8+j)
    bf16x8 qf[2][2];
#pragma unroll
    for (int rt = 0; rt < 2; ++rt)
#pragma unroll
        for (int kc = 0; kc < 2; ++kc) {
            int row = q0 + w * 32 + rt * 16 + m16;
            qf[rt][kc] = ld8(Qg + (size_t)row * 64 + (quad + 4 * kc) * 8);
        }

    fx4 Oacc[2][4] = {};
    float m_[2][4], l_[2][4];
#pragma unroll
    for (int rt = 0; rt < 2; ++rt)
#pragma unroll
        for (int r = 0; r < 4; ++r) { m_[rt][r] = -INFINITY; l_[rt][r] = 0.0f; }

    for (int it = 0; it < 64; ++it) {
        int k0 = it * 64;
        __syncthreads();   // previous iter's K/V reads done
#pragma unroll
        for (int j = 0; j < 2; ++j) {
            int L = tid + j * 256;
            int row = L >> 3, c = L & 7;
            *(int4*)&Ks[row * 72 + c * 8] = *(const int4*)(Kg + (size_t)(k0 + row) * 64 + c * 8);
            *(int4*)&Vs[row * 72 + c * 8] = *(const int4*)(Vg + (size_t)row * 4096 + k0 + c * 8);
        }
        __syncthreads();

        // S = Q K^T  (scale pre-folded into Q)
        fx4 S[2][4] = {};
#pragma unroll
        for (int kc = 0; kc < 2; ++kc)
#pragma unroll
            for (int ct = 0; ct < 4; ++ct) {
                bf16x8 kf = ld8(&Ks[(ct * 16 + m16) * 72 + (quad + 4 * kc) * 8]);
                S[0][ct] = __builtin_amdgcn_mfma_f32_16x16x32_bf16(qf[0][kc], kf, S[0][ct], 0, 0, 0);
                S[1][ct] = __builtin_amdgcn_mfma_f32_16x16x32_bf16(qf[1][kc], kf, S[1][ct], 0, 0, 0);
            }

        // online softmax in C-layout (row = quad*4+r, col = ct*16+m16)
#pragma unroll
        for (int rt = 0; rt < 2; ++rt) {
            float a_r[4];
#pragma unroll
            for (int r = 0; r < 4; ++r) {
                float mx = fmaxf(fmaxf(S[rt][0][r], S[rt][1][r]), fmaxf(S[rt][2][r], S[rt][3][r]));
                mx = rowmax16(mx);
                float mn = fmaxf(m_[rt][r], mx);
                float al = __expf(m_[rt][r] - mn);
                m_[rt][r] = mn;
                float ps = 0.0f;
                int prow = (w * 32 + rt * 16 + quad * 4 + r) * 72;
#pragma unroll
                for (int ct = 0; ct < 4; ++ct) {
                    float p = __expf(S[rt][ct][r] - mn);
                    ps += p;
                    Ps[prow + ct * 16 + m16] = f2bf(p);
                }
                ps = rowsum16(ps);
                l_[rt][r] = l_[rt][r] * al + ps;
                a_r[r] = al;
            }
#pragma unroll
            for (int ctd = 0; ctd < 4; ++ctd)
#pragma unroll
                for (int r = 0; r < 4; ++r)
                    Oacc[rt][ctd][r] *= a_r[r];
        }

        // O += P V   (P via LDS: A-layout; V^T rows give B-layout)
#pragma unroll
        for (int kc = 0; kc < 2; ++kc) {
            bf16x8 pf0 = ld8(&Ps[(w * 32 + m16) * 72 + (quad + 4 * kc) * 8]);
            bf16x8 pf1 = ld8(&Ps[(w * 32 + 16 + m16) * 72 + (quad + 4 * kc) * 8]);
#pragma unroll
            for (int ctd = 0; ctd < 4; ++ctd) {
                bf16x8 vf = ld8(&Vs[(ctd * 16 + m16) * 72 + (quad + 4 * kc) * 8]);
                Oacc[0][ctd] = __builtin_amdgcn_mfma_f32_16x16x32_bf16(pf0, vf, Oacc[0][ctd], 0, 0, 0);
                Oacc[1][ctd] = __builtin_amdgcn_mfma_f32_16x16x32_bf16(pf1, vf, Oacc[1][ctd], 0, 0, 0);
            }
        }
    }

    // epilogue: O /= l, write [B, N, H*Dh] bf16
    int b = bh >> 3, h = bh & 7;
#pragma unroll
    for (int rt = 0; rt < 2; ++rt)
#pragma unroll
        for (int r = 0; r < 4; ++r) {
            float inv = 1.0f / l_[rt][r];
            int n = q0 + w * 32 + rt * 16 + quad * 4 + r;
            size_t base = ((size_t)(b * 4096 + n)) * 512 + h * 64;
#pragma unroll
            for (int ctd = 0; ctd < 4; ++ctd)
                Ob[base + ctd * 16 + m16] = f2bf(Oacc[rt][ctd][r] * inv);
        }
}

// ---------------- launcher ----------------

extern "C" void kernel_launch(void* const* d_in, const int* in_sizes, int n_in,
                              void* d_out, int out_size, void* d_ws, size_t ws_size,
                              hipStream_t stream) {
    const float* x     = (const float*)d_in[0];   // [2,4096,512]
    const float* w_qkv = (const float*)d_in[1];   // [512,1536]
    const float* w_out = (const float*)d_in[2];   // [512,512]
    const float* b_out = (const float*)d_in[3];   // [512]
    float* out = (float*)d_out;                   // [2,4096,512] fp32

    char* ws = (char*)d_ws;
    u16* x_b    = (u16*)(ws);                     //  8 MB
    u16* wqkv_t = (u16*)(ws + 8388608);           //  1.5 MB  [1536][512]
    u16* wout_t = (u16*)(ws + 9961472);           //  0.5 MB  [512][512]
    u16* Qb     = (u16*)(ws + 10485760);          //  8 MB [16][4096][64] (pre-scaled)
    u16* Kb     = (u16*)(ws + 18874368);          //  8 MB [16][4096][64]
    u16* Vt     = (u16*)(ws + 27262976);          //  8 MB [16][64][4096]
    u16* Ob     = (u16*)(ws + 35651584);          //  8 MB [8192][512]

    cast_x_kernel<<<2048, 256, 0, stream>>>(x, x_b);
    transpose_cast_kernel<<<dim3(24, 8), 256, 0, stream>>>(w_qkv, wqkv_t, 512, 1536);
    transpose_cast_kernel<<<dim3(8, 8), 256, 0, stream>>>(w_out, wout_t, 512, 512);
    gemm_kernel<0><<<768, 256, 0, stream>>>(x_b, wqkv_t, Qb, Kb, Vt, nullptr, nullptr, 1536);
    attn_kernel<<<512, 256, 0, stream>>>(Qb, Kb, Vt, Ob);
    gemm_kernel<1><<<256, 256, 0, stream>>>(Ob, wout_t, nullptr, nullptr, nullptr, b_out, out, 512);
}